// Round 1
// baseline (2484.103 us; speedup 1.0000x reference)
//
#include <hip/hip_runtime.h>

namespace {

constexpr int T_LEN = 2048;
constexpr int B_TOT = 2048;
constexpr int H1 = 36;
constexpr int NG = 4 * H1;      // 144 gates per batch
constexpr int NB = 4;           // batches per block
constexpr int NGT = NB * NG;    // 576 gate threads
constexpr int BLOCK = NGT + 64; // + dedicated layer-2 wave = 640 (10 waves)

__device__ __forceinline__ float fexp2(float x) { return __builtin_amdgcn_exp2f(x); }
__device__ __forceinline__ float frcp(float x) { return __builtin_amdgcn_rcpf(x); }
__device__ __forceinline__ float sigm(float x) {
  return frcp(1.0f + fexp2(x * -1.44269504f));
}
__device__ __forceinline__ float tanh_fast(float x) {
  // tanh(x) = 2*sigmoid(2x) - 1
  return fmaf(2.0f, frcp(1.0f + fexp2(x * -2.88539008f)), -1.0f);
}

__global__ __launch_bounds__(BLOCK, 5) void lstm2_kernel(
    const float* __restrict__ x,
    const float* __restrict__ Wih1,
    const float* __restrict__ Whh1,
    const float* __restrict__ bih1,
    const float* __restrict__ bhh1,
    const float* __restrict__ Wih2,
    const float* __restrict__ Whh2,
    const float* __restrict__ bih2,
    const float* __restrict__ bhh2,
    float* __restrict__ out)
{
  __shared__ __align__(16) float sh_h[NB * H1];     // h1 state per batch
  __shared__ __align__(16) float sh_relu[NB * H1];  // relu(h1) for layer 2
  __shared__ __align__(16) float sh_gate[NB * NG];  // activated layer-1 gates

  const int tid = threadIdx.x;
  const int bid = blockIdx.x;

  // Role-dependent persistent registers (uniform declarations, guarded init).
  float4 w4[9];                 // phase1: W_hh1 row / L2 wave: W_ih2 row
  float wB = 0.f, biasC = 0.f;  // phase1: W_ih1[g], b1[g] / L2: W_hh2[j], b2[j]
  float escale = -1.44269504f, amul = 1.f, aadd = 0.f;
  const float* xp = nullptr;
  float* outp = nullptr;
  int hbase = 0;  // LDS row offset (h for phase1 / relu for L2 wave)
  int gbase = 0;  // phase2 gate read base

#pragma unroll
  for (int q = 0; q < 9; ++q) w4[q] = make_float4(0.f, 0.f, 0.f, 0.f);

  if (tid < NGT) {
    const int b1 = tid / NG;       // local batch 0..3
    const int g = tid - b1 * NG;   // gate 0..143
    const int gt = g / H1;         // 0=i 1=f 2=g 3=o
    const float4* wrow = (const float4*)(Whh1 + g * H1);  // rows are 16B-aligned (36*4B=144B)
#pragma unroll
    for (int q = 0; q < 9; ++q) w4[q] = wrow[q];
    wB = Wih1[g];                  // D=1: column vector
    biasC = bih1[g] + bhh1[g];
    if (gt == 2) { escale = -2.88539008f; amul = 2.f; aadd = -1.f; }  // tanh gate
    xp = x + (size_t)(bid * NB + b1) * T_LEN;
    hbase = b1 * H1;
  } else {
    const int l = tid - NGT;
    if (l < 16) {
      const int j = l & 3;    // layer-2 gate index
      const int bq = l >> 2;  // local batch
      const float4* wrow = (const float4*)(Wih2 + j * H1);
#pragma unroll
      for (int q = 0; q < 9; ++q) w4[q] = wrow[q];
      wB = Whh2[j];
      biasC = bih2[j] + bhh2[j];
      outp = out + (size_t)(bid * NB + bq) * T_LEN;
      hbase = bq * H1;
    }
  }
  if (tid < NB * H1) gbase = (tid / H1) * NG + (tid % H1);  // phase2 role

  float c1 = 0.f;            // layer-1 cell, owned by threads 0..143 (unit tid%36, batch tid/36)
  float c2 = 0.f, h2 = 0.f;  // layer-2 state, owned by L2 wave lanes
  float4 ov = make_float4(0.f, 0.f, 0.f, 0.f);
  float4 xc = make_float4(0.f, 0.f, 0.f, 0.f);
  if (tid < NGT) xc = *(const float4*)xp;  // t = 0..3

  if (tid < NB * H1) sh_h[tid] = 0.f;  // h0 = 0
  __syncthreads();

  auto substep = [&](float xv, int s) {
    // ---- phase 1: all 576 gate threads ----
    if (tid < NGT) {
      float a0 = fmaf(xv, wB, biasC);
      float a1 = 0.f, a2 = 0.f, a3 = 0.f;
      const float4* h4 = (const float4*)(sh_h + hbase);  // broadcast reads
#pragma unroll
      for (int q = 0; q < 9; ++q) {
        float4 hq = h4[q];
        a0 = fmaf(w4[q].x, hq.x, a0);
        a1 = fmaf(w4[q].y, hq.y, a1);
        a2 = fmaf(w4[q].z, hq.z, a2);
        a3 = fmaf(w4[q].w, hq.w, a3);
      }
      float pre = (a0 + a1) + (a2 + a3);
      // branchless sigmoid (i,f,o) / tanh (g)
      sh_gate[tid] = fmaf(amul, frcp(1.f + fexp2(pre * escale)), aadd);
    }
    __syncthreads();  // A: gates visible
    // ---- phase 2: 144 unit threads update c1, h1 ----
    if (tid < NB * H1) {
      float gi = sh_gate[gbase];
      float gf = sh_gate[gbase + H1];
      float gg = sh_gate[gbase + 2 * H1];
      float go = sh_gate[gbase + 3 * H1];
      c1 = fmaf(gf, c1, gi * gg);
      float hv = go * tanh_fast(c1);
      sh_h[tid] = hv;                  // tid == b*36+u: layout matches
      sh_relu[tid] = fmaxf(hv, 0.f);
    }
    __syncthreads();  // B: h, relu(h) visible
    // ---- layer 2: dedicated wave, overlaps next step's phase 1 ----
    if (tid >= NGT) {
      const int l = tid - NGT;
      if (l < 16) {
        float acc = fmaf(h2, wB, biasC);
        const float4* r4 = (const float4*)(sh_relu + hbase);
#pragma unroll
        for (int q = 0; q < 9; ++q) {
          float4 rq = r4[q];
          acc = fmaf(w4[q].x, rq.x, acc);
          acc = fmaf(w4[q].y, rq.y, acc);
          acc = fmaf(w4[q].z, rq.z, acc);
          acc = fmaf(w4[q].w, rq.w, acc);
        }
        const int base = l & 0x0c;  // first lane of this batch's 4-lane group
        float gi = __shfl(acc, base + 0);
        float gf = __shfl(acc, base + 1);
        float gg = __shfl(acc, base + 2);
        float go = __shfl(acc, base + 3);
        c2 = fmaf(sigm(gf), c2, sigm(gi) * tanh_fast(gg));
        h2 = sigm(go) * tanh_fast(c2);
        if (s == 0)      ov.x = h2;
        else if (s == 1) ov.y = h2;
        else if (s == 2) ov.z = h2;
        else             ov.w = h2;
      }
    }
  };

  for (int t0 = 0; t0 < T_LEN; t0 += 4) {
    float4 xn = xc;
    if (tid < NGT) {  // prefetch next x group
      const int tn = (t0 + 4 < T_LEN) ? (t0 + 4) : t0;
      xn = *(const float4*)(xp + tn);
    }
    substep(xc.x, 0);
    substep(xc.y, 1);
    substep(xc.z, 2);
    substep(xc.w, 3);
    if (tid >= NGT) {
      const int l = tid - NGT;
      if (l < 16 && (l & 3) == 0) {
        *(float4*)(outp + t0) = ov;  // 16B-aligned (t0 % 4 == 0)
      }
    }
    xc = xn;
  }
}

}  // namespace

extern "C" void kernel_launch(void* const* d_in, const int* in_sizes, int n_in,
                              void* d_out, int out_size, void* d_ws, size_t ws_size,
                              hipStream_t stream) {
  const float* x    = (const float*)d_in[0];
  const float* Wih1 = (const float*)d_in[1];
  const float* Whh1 = (const float*)d_in[2];
  const float* bih1 = (const float*)d_in[3];
  const float* bhh1 = (const float*)d_in[4];
  const float* Wih2 = (const float*)d_in[5];
  const float* Whh2 = (const float*)d_in[6];
  const float* bih2 = (const float*)d_in[7];
  const float* bhh2 = (const float*)d_in[8];
  float* out = (float*)d_out;

  dim3 grid(B_TOT / NB);  // 512 blocks, 2 per CU
  dim3 block(BLOCK);      // 640 threads = 10 waves
  hipLaunchKernelGGL(lstm2_kernel, grid, block, 0, stream,
                     x, Wih1, Whh1, bih1, bhh1, Wih2, Whh2, bih2, bhh2, out);
}

// Round 2
// 1415.060 us; speedup vs baseline: 1.7555x; 1.7555x over previous
//
#include <hip/hip_runtime.h>

namespace {

constexpr int T_LEN = 2048;
constexpr int B_TOT = 2048;
constexpr int H1 = 36;
constexpr int NBATCH = 8;              // batches per block
constexpr int PHA = NBATCH * H1 * 2;   // 576 phase-A threads (b, u, K-half)
constexpr int BLOCK = PHA + 64;        // + 1 dedicated layer-2 wave = 640
constexpr int HFL = NBATCH * H1 + 8;   // 296 floats per h buffer (+pad for over-read)
constexpr int HQ = HFL / 4;            // 74 float4 per buffer

__device__ __forceinline__ float fexp2(float x) { return __builtin_amdgcn_exp2f(x); }
__device__ __forceinline__ float frcp(float x) { return __builtin_amdgcn_rcpf(x); }
__device__ __forceinline__ float sigm(float x) { return frcp(1.f + fexp2(x * -1.44269504f)); }
__device__ __forceinline__ float tanh_fast(float x) {
  // tanh(x) = 2*sigmoid(2x) - 1; saturates correctly for |x| large
  return fmaf(2.f, frcp(1.f + fexp2(x * -2.88539008f)), -1.f);
}

__global__ __launch_bounds__(BLOCK, 3) void lstm2_kernel(
    const float* __restrict__ x, const float* __restrict__ Wih1,
    const float* __restrict__ Whh1, const float* __restrict__ bih1,
    const float* __restrict__ bhh1, const float* __restrict__ Wih2,
    const float* __restrict__ Whh2, const float* __restrict__ bih2,
    const float* __restrict__ bhh2, float* __restrict__ out)
{
  __shared__ __align__(16) float sh[2 * HFL];  // double-buffered h1 state

  const int tid = threadIdx.x;
  const bool isA = tid < PHA;

  // Persistent registers (uniform declarations, role-guarded init).
  float4 w[4][5];              // phase A: W_hh1 half-rows for 4 gates; L2: w[0]=W_ih2 half-row
  float wB[4] = {0, 0, 0, 0};  // phase A: W_ih1[g]; L2: wB[0]=W_hh2[j]
  float bias[4] = {0, 0, 0, 0};
  const float* xp = nullptr;
  float* outp = nullptr;
  int rdq = 0;     // float4 read index within a buffer: b*9 + p*5
  int wri = 0;     // h write index: b*36 + u
  int p = 0;       // K-half (0: k=0..19, 1: k=20..35 + zero-padded quad)
  int l2base = 0;  // L2 gather base lane

#pragma unroll
  for (int g = 0; g < 4; ++g)
#pragma unroll
    for (int q = 0; q < 5; ++q) w[g][q] = make_float4(0.f, 0.f, 0.f, 0.f);

  if (isA) {
    const int b = tid / 72;
    const int r = tid - b * 72;
    const int u = r >> 1;
    p = r & 1;
#pragma unroll
    for (int g = 0; g < 4; ++g) {
      const int row = g * H1 + u;
      const float* wr = Whh1 + row * H1 + p * 20;
#pragma unroll
      for (int q = 0; q < 5; ++q)
        if (p * 20 + 4 * q < H1) w[g][q] = *(const float4*)(wr + 4 * q);
      wB[g] = Wih1[row];
      bias[g] = bih1[row] + bhh1[row];
    }
    xp = x + (size_t)(blockIdx.x * NBATCH + b) * T_LEN;
    rdq = b * 9 + p * 5;
    wri = b * H1 + u;
  } else {
    const int l = tid - PHA;        // lane within L2 wave (PHA = 9*64)
    const int b = l >> 3;           // local batch 0..7
    const int j = (l >> 1) & 3;     // layer-2 gate
    p = l & 1;
    const float* wr = Wih2 + j * H1 + p * 20;
#pragma unroll
    for (int q = 0; q < 5; ++q)
      if (p * 20 + 4 * q < H1) w[0][q] = *(const float4*)(wr + 4 * q);
    wB[0] = Whh2[j];
    bias[0] = bih2[j] + bhh2[j];
    outp = out + (size_t)(blockIdx.x * NBATCH + b) * T_LEN;
    rdq = b * 9 + p * 5;
    l2base = l & 56;
  }

  float c1 = 0.f, c2 = 0.f, h2 = 0.f;
  float4 ov = make_float4(0.f, 0.f, 0.f, 0.f);
  float4 xq = make_float4(0.f, 0.f, 0.f, 0.f);
  if (isA) xq = *(const float4*)xp;

  for (int i = tid; i < 2 * HFL; i += BLOCK) sh[i] = 0.f;  // h0 = 0 (+pad)
  __syncthreads();

  // ---- phase A: compute h1_t for (b, u); both K-halves, combined via shfl ----
  auto astep = [&](int t, float xv) {
    const int cur = t & 1, nxt = cur ^ 1;
    const float4* hp = (const float4*)sh + cur * HQ + rdq;
    float a0, a1, a2, a3;
    if (p == 0) {
      a0 = fmaf(xv, wB[0], bias[0]);
      a1 = fmaf(xv, wB[1], bias[1]);
      a2 = fmaf(xv, wB[2], bias[2]);
      a3 = fmaf(xv, wB[3], bias[3]);
    } else {
      a0 = a1 = a2 = a3 = 0.f;
    }
#pragma unroll
    for (int q = 0; q < 5; ++q) {
      float4 hq = hp[q];  // 2-ish distinct addrs per wave; p=1 q=4 is garbage*0
      a0 = fmaf(w[0][q].x, hq.x, a0);
      a1 = fmaf(w[1][q].x, hq.x, a1);
      a2 = fmaf(w[2][q].x, hq.x, a2);
      a3 = fmaf(w[3][q].x, hq.x, a3);
      a0 = fmaf(w[0][q].y, hq.y, a0);
      a1 = fmaf(w[1][q].y, hq.y, a1);
      a2 = fmaf(w[2][q].y, hq.y, a2);
      a3 = fmaf(w[3][q].y, hq.y, a3);
      a0 = fmaf(w[0][q].z, hq.z, a0);
      a1 = fmaf(w[1][q].z, hq.z, a1);
      a2 = fmaf(w[2][q].z, hq.z, a2);
      a3 = fmaf(w[3][q].z, hq.z, a3);
      a0 = fmaf(w[0][q].w, hq.w, a0);
      a1 = fmaf(w[1][q].w, hq.w, a1);
      a2 = fmaf(w[2][q].w, hq.w, a2);
      a3 = fmaf(w[3][q].w, hq.w, a3);
    }
    a0 += __shfl_xor(a0, 1);
    a1 += __shfl_xor(a1, 1);
    a2 += __shfl_xor(a2, 1);
    a3 += __shfl_xor(a3, 1);
    const float gi = sigm(a0), gf = sigm(a1), gg = tanh_fast(a2), go = sigm(a3);
    c1 = fmaf(gf, c1, gi * gg);
    const float hv = go * tanh_fast(c1);
    if (p == 0) sh[nxt * HFL + wri] = hv;
  };

  // ---- layer 2: computes out[t-1] from h1_{t-1} in buffer (t&1) ----
  auto l2step = [&](int t, int s) {
    const int cur = t & 1;
    const float4* hp = (const float4*)sh + cur * HQ + rdq;
    float acc = 0.f;
#pragma unroll
    for (int q = 0; q < 5; ++q) {
      float4 hq = hp[q];
      acc = fmaf(w[0][q].x, fmaxf(hq.x, 0.f), acc);
      acc = fmaf(w[0][q].y, fmaxf(hq.y, 0.f), acc);
      acc = fmaf(w[0][q].z, fmaxf(hq.z, 0.f), acc);
      acc = fmaf(w[0][q].w, fmaxf(hq.w, 0.f), acc);
    }
    acc += __shfl_xor(acc, 1);
    const float pre = acc + fmaf(h2, wB[0], bias[0]);
    const float gi = __shfl(pre, l2base + 0);
    const float gf = __shfl(pre, l2base + 2);
    const float gg = __shfl(pre, l2base + 4);
    const float go = __shfl(pre, l2base + 6);
    c2 = fmaf(sigm(gf), c2, sigm(gi) * tanh_fast(gg));
    h2 = sigm(go) * tanh_fast(c2);
    if (s == 0) {
      ov.w = h2;
      if ((tid & 7) == 0) *(float4*)(outp + t - 4) = ov;
    } else if (s == 1) ov.x = h2;
    else if (s == 2)   ov.y = h2;
    else               ov.z = h2;
  };

  for (int t0 = 0; t0 < T_LEN; t0 += 4) {
    float4 xn = xq;
    if (isA) {
      const int tn = (t0 + 4 < T_LEN) ? (t0 + 4) : t0;
      xn = *(const float4*)(xp + tn);
    }
    if (isA) astep(t0, xq.x); else if (t0 > 0) l2step(t0, 0);
    __syncthreads();
    if (isA) astep(t0 + 1, xq.y); else l2step(t0 + 1, 1);
    __syncthreads();
    if (isA) astep(t0 + 2, xq.z); else l2step(t0 + 2, 2);
    __syncthreads();
    if (isA) astep(t0 + 3, xq.w); else l2step(t0 + 3, 3);
    __syncthreads();
    xq = xn;
  }
  if (!isA) l2step(T_LEN, 0);  // final out[T-1] + store last quad
}

}  // namespace

extern "C" void kernel_launch(void* const* d_in, const int* in_sizes, int n_in,
                              void* d_out, int out_size, void* d_ws, size_t ws_size,
                              hipStream_t stream) {
  const float* x    = (const float*)d_in[0];
  const float* Wih1 = (const float*)d_in[1];
  const float* Whh1 = (const float*)d_in[2];
  const float* bih1 = (const float*)d_in[3];
  const float* bhh1 = (const float*)d_in[4];
  const float* Wih2 = (const float*)d_in[5];
  const float* Whh2 = (const float*)d_in[6];
  const float* bih2 = (const float*)d_in[7];
  const float* bhh2 = (const float*)d_in[8];
  float* out = (float*)d_out;

  dim3 grid(B_TOT / NBATCH);  // 256 blocks -> 1 per CU
  dim3 block(BLOCK);          // 640 threads = 10 waves
  hipLaunchKernelGGL(lstm2_kernel, grid, block, 0, stream,
                     x, Wih1, Whh1, bih1, bhh1, Wih2, Whh2, bih2, bhh2, out);
}

// Round 3
// 1337.725 us; speedup vs baseline: 1.8570x; 1.0578x over previous
//
#include <hip/hip_runtime.h>

namespace {

constexpr int T_LEN = 2048;
constexpr int B_TOT = 2048;
constexpr int H1 = 36;
constexpr int NBATCH = 8;             // batches per block
constexpr int PHA = NBATCH * H1 * 2;  // 576 phase-A threads: (b, u, K-half)
constexpr int BLOCK = PHA + 64;       // + dedicated layer-2 wave = 640 (10 waves)
constexpr int HFL = NBATCH * H1;      // 288 floats per h buffer (no pad needed: 18/18 split)

typedef float f32x2 __attribute__((ext_vector_type(2)));

__device__ __forceinline__ f32x2 pk_fma(f32x2 a, f32x2 b, f32x2 c) {
  f32x2 d;
  asm("v_pk_fma_f32 %0, %1, %2, %3" : "=v"(d) : "v"(a), "v"(b), "v"(c));
  return d;
}

__device__ __forceinline__ float fexp2(float x) { return __builtin_amdgcn_exp2f(x); }
__device__ __forceinline__ float frcp(float x) { return __builtin_amdgcn_rcpf(x); }
__device__ __forceinline__ float sigm(float x) { return frcp(1.f + fexp2(x * -1.44269504f)); }
__device__ __forceinline__ float tanh_fast(float x) {
  return fmaf(2.f, frcp(1.f + fexp2(x * -2.88539008f)), -1.f);  // 2*sigm(2x)-1
}

__global__ __launch_bounds__(BLOCK, 3) void lstm2_kernel(
    const float* __restrict__ x, const float* __restrict__ Wih1,
    const float* __restrict__ Whh1, const float* __restrict__ bih1,
    const float* __restrict__ bhh1, const float* __restrict__ Wih2,
    const float* __restrict__ Whh2, const float* __restrict__ bih2,
    const float* __restrict__ bhh2, float* __restrict__ out)
{
  __shared__ __align__(16) float sh[2 * HFL];  // double-buffered h1 state

  const int tid = threadIdx.x;
  const bool isA = tid < PHA;

  // Persistent registers (uniform declarations, role-guarded init).
  f32x2 wv[4][9];              // A: W_hh1 K-half rows (4 gates x 18); L2: wv[0] = W_ih2 half
  float wB[4] = {0, 0, 0, 0};  // A: W_ih1[g] (p=0 only; p=1 zeroed); L2: wB[0] = W_hh2[j]
  float bias[4] = {0, 0, 0, 0};
  const float* xp = nullptr;
  float* outp = nullptr;
  int rdh = 0;   // f32x2 read index within a buffer: b*18 + p*9
  int wri = 0;   // h write index: b*36 + u
  int p = 0;     // K-half: p=0 -> k 0..17, p=1 -> k 18..35
  int l2base = 0;
  // Per-lane activation constants for the gate-split nonlinearity:
  // p=0 applies sigmoid to (i); p=1 applies tanh to (g). Second act is sigmoid for both.
  float es0 = -1.44269504f, am0 = 1.f, aa0 = 0.f;

#pragma unroll
  for (int g = 0; g < 4; ++g)
#pragma unroll
    for (int q = 0; q < 9; ++q) wv[g][q] = (f32x2){0.f, 0.f};

  if (isA) {
    const int b = tid / 72;
    const int r = tid - b * 72;
    const int u = r >> 1;
    p = r & 1;
#pragma unroll
    for (int g = 0; g < 4; ++g) {
      const int row = g * H1 + u;
      const float* wr = Whh1 + row * H1 + p * 18;
#pragma unroll
      for (int q = 0; q < 9; ++q) wv[g][q] = *(const f32x2*)(wr + 2 * q);
      if (p == 0) {
        wB[g] = Wih1[row];
        bias[g] = bih1[row] + bhh1[row];
      }
    }
    if (p == 1) { es0 = -2.88539008f; am0 = 2.f; aa0 = -1.f; }  // tanh for g-gate
    xp = x + (size_t)(blockIdx.x * NBATCH + b) * T_LEN;
    rdh = b * 18 + p * 9;
    wri = b * H1 + u;
  } else {
    const int l = tid - PHA;     // 0..63
    const int b = l >> 3;        // local batch
    const int j = (l >> 1) & 3;  // layer-2 gate
    p = l & 1;
    const float* wr = Wih2 + j * H1 + p * 18;
#pragma unroll
    for (int q = 0; q < 9; ++q) wv[0][q] = *(const f32x2*)(wr + 2 * q);
    wB[0] = Whh2[j];
    bias[0] = bih2[j] + bhh2[j];
    outp = out + (size_t)(blockIdx.x * NBATCH + b) * T_LEN;
    rdh = b * 18 + p * 9;
    l2base = l & 56;
  }

  float c1 = 0.f, c2 = 0.f, h2 = 0.f;
  float4 ov = make_float4(0.f, 0.f, 0.f, 0.f);
  float4 xq = make_float4(0.f, 0.f, 0.f, 0.f);
  if (isA) xq = *(const float4*)xp;

  for (int i = tid; i < 2 * HFL; i += BLOCK) sh[i] = 0.f;  // h0 = 0
  __syncthreads();

  // ---- phase A: h1_t for (b,u); K-split dot (pk_fma), gate-split activations ----
  auto astep = [&](int cur, float xv) {
    const f32x2* hp = (const f32x2*)(sh + cur * HFL) + rdh;
    f32x2 h[9];
#pragma unroll
    for (int q = 0; q < 9; ++q) h[q] = hp[q];
    f32x2 a0 = {fmaf(xv, wB[0], bias[0]), 0.f};
    f32x2 a1 = {fmaf(xv, wB[1], bias[1]), 0.f};
    f32x2 a2 = {fmaf(xv, wB[2], bias[2]), 0.f};
    f32x2 a3 = {fmaf(xv, wB[3], bias[3]), 0.f};
#pragma unroll
    for (int q = 0; q < 9; ++q) {
      a0 = pk_fma(wv[0][q], h[q], a0);
      a1 = pk_fma(wv[1][q], h[q], a1);
      a2 = pk_fma(wv[2][q], h[q], a2);
      a3 = pk_fma(wv[3][q], h[q], a3);
    }
    const float s0 = a0.x + a0.y, s1 = a1.x + a1.y;
    const float s2 = a2.x + a2.y, s3 = a3.x + a3.y;
    // Exchange partials: p=0 ends with full (i,f); p=1 with full (g,o).
    const float r0 = __shfl_xor(p ? s0 : s2, 1);
    const float r1 = __shfl_xor(p ? s1 : s3, 1);
    const float own0 = (p ? s2 : s0) + r0;  // p0: pre_i, p1: pre_g
    const float own1 = (p ? s3 : s1) + r1;  // p0: pre_f, p1: pre_o
    // Per-lane activation (branchless): p0 -> sigm, p1 -> tanh for own0; sigm for own1.
    const float t0v = fmaf(am0, frcp(1.f + fexp2(own0 * es0)), aa0);  // p0: I, p1: G
    const float t1v = sigm(own1);                                     // p0: F, p1: O
    const float gI = __shfl_xor(t0v, 1);  // p0 receives G
    c1 = fmaf(t1v, c1, t0v * gI);         // p0: F*c + I*G (p1: benign garbage, bounded)
    const float th = tanh_fast(c1);
    const float oG = __shfl_xor(t1v, 1);  // p0 receives O
    if (p == 0) sh[(cur ^ 1) * HFL + wri] = oG * th;
  };

  // ---- layer 2: out[t-1] from h1_{t-1} in buffer `cur`; runs while A computes h_t ----
  auto l2step = [&](int cur, int t, int s) {
    const f32x2* hp = (const f32x2*)(sh + cur * HFL) + rdh;
    f32x2 acc = {0.f, 0.f};
#pragma unroll
    for (int q = 0; q < 9; ++q) {
      f32x2 hq = hp[q];
      f32x2 rl = {fmaxf(hq.x, 0.f), fmaxf(hq.y, 0.f)};
      acc = pk_fma(wv[0][q], rl, acc);
    }
    float sum = acc.x + acc.y;
    sum += __shfl_xor(sum, 1);
    const float pre = sum + fmaf(h2, wB[0], bias[0]);
    const float gi = __shfl(pre, l2base + 0);
    const float gf = __shfl(pre, l2base + 2);
    const float gg = __shfl(pre, l2base + 4);
    const float go = __shfl(pre, l2base + 6);
    c2 = fmaf(sigm(gf), c2, sigm(gi) * tanh_fast(gg));
    h2 = sigm(go) * tanh_fast(c2);
    if (s == 0) {
      ov.w = h2;
      if ((tid & 7) == 0) *(float4*)(outp + t - 4) = ov;
    } else if (s == 1) ov.x = h2;
    else if (s == 2)   ov.y = h2;
    else               ov.z = h2;
  };

  for (int t0 = 0; t0 < T_LEN; t0 += 4) {
    float4 xn = xq;
    if (isA) {
      const int tn = (t0 + 4 < T_LEN) ? (t0 + 4) : t0;
      xn = *(const float4*)(xp + tn);
    }
    if (isA) astep(0, xq.x); else if (t0 > 0) l2step(0, t0, 0);
    __syncthreads();
    if (isA) astep(1, xq.y); else l2step(1, t0 + 1, 1);
    __syncthreads();
    if (isA) astep(0, xq.z); else l2step(0, t0 + 2, 2);
    __syncthreads();
    if (isA) astep(1, xq.w); else l2step(1, t0 + 3, 3);
    __syncthreads();
    xq = xn;
  }
  if (!isA) l2step(0, T_LEN, 0);  // out[T-1] + final quad store
}

}  // namespace

extern "C" void kernel_launch(void* const* d_in, const int* in_sizes, int n_in,
                              void* d_out, int out_size, void* d_ws, size_t ws_size,
                              hipStream_t stream) {
  const float* x    = (const float*)d_in[0];
  const float* Wih1 = (const float*)d_in[1];
  const float* Whh1 = (const float*)d_in[2];
  const float* bih1 = (const float*)d_in[3];
  const float* bhh1 = (const float*)d_in[4];
  const float* Wih2 = (const float*)d_in[5];
  const float* Whh2 = (const float*)d_in[6];
  const float* bih2 = (const float*)d_in[7];
  const float* bhh2 = (const float*)d_in[8];
  float* out = (float*)d_out;

  dim3 grid(B_TOT / NBATCH);  // 256 blocks -> 1 per CU
  dim3 block(BLOCK);          // 640 threads = 10 waves
  hipLaunchKernelGGL(lstm2_kernel, grid, block, 0, stream,
                     x, Wih1, Whh1, bih1, bhh1, Wih2, Whh2, bih2, bhh2, out);
}

// Round 4
// 1084.794 us; speedup vs baseline: 2.2899x; 1.2332x over previous
//
#include <hip/hip_runtime.h>

namespace {

constexpr int T_LEN = 2048;
constexpr int B_TOT = 2048;
constexpr int H1 = 36;                 // layer-1 units; lane 36 = layer-2 LSTM
constexpr int WPB = 4;                 // waves (=batches) per block
constexpr int BLOCK = 64 * WPB;
constexpr int LDSW = 128;              // floats per wave region: h[64] + relu[64]

typedef float f32x2 __attribute__((ext_vector_type(2)));

__device__ __forceinline__ f32x2 pk_fma(f32x2 a, f32x2 b, f32x2 c) {
  f32x2 d;
  asm("v_pk_fma_f32 %0, %1, %2, %3" : "=v"(d) : "v"(a), "v"(b), "v"(c));
  return d;
}
__device__ __forceinline__ f32x2 pk_mul(f32x2 a, f32x2 b) {
  f32x2 d;
  asm("v_pk_mul_f32 %0, %1, %2" : "=v"(d) : "v"(a), "v"(b));
  return d;
}

__device__ __forceinline__ float fexp2(float x) { return __builtin_amdgcn_exp2f(x); }
__device__ __forceinline__ float frcp(float x) { return __builtin_amdgcn_rcpf(x); }
__device__ __forceinline__ float sigm(float x) { return frcp(1.f + fexp2(x * -1.44269504f)); }
__device__ __forceinline__ float tanh_fast(float x) {
  return fmaf(2.f, frcp(1.f + fexp2(x * -2.88539008f)), -1.f);  // 2*sigm(2x)-1
}

__global__ __launch_bounds__(BLOCK, 2) void lstm2_kernel(
    const float* __restrict__ x, const float* __restrict__ Wih1,
    const float* __restrict__ Whh1, const float* __restrict__ bih1,
    const float* __restrict__ bhh1, const float* __restrict__ Wih2,
    const float* __restrict__ Whh2, const float* __restrict__ bih2,
    const float* __restrict__ bhh2, float* __restrict__ out)
{
  __shared__ __align__(16) float sh[WPB * LDSW];

  const int tid = threadIdx.x;
  const int w = tid >> 6;
  const int lane = tid & 63;
  const int batch = blockIdx.x * WPB + w;

  float* shh = sh + w * LDSW;   // h1 state, indices 0..35 live (36..63 = dump)
  float* shr = shh + 64;        // relu(h1) copy for the L2 lane

  const bool isA = lane < H1;
  const bool isL2 = lane == H1;

  // Per-lane weights: lane u<36 -> 4 rows of W_hh1; lane 36 -> 4 rows of W_ih2.
  f32x2 wv[4][18];
  float wB[4] = {0, 0, 0, 0}, bias[4] = {0, 0, 0, 0};
#pragma unroll
  for (int g = 0; g < 4; ++g)
#pragma unroll
    for (int k = 0; k < 18; ++k) wv[g][k] = (f32x2){0.f, 0.f};

  if (isA) {
#pragma unroll
    for (int g = 0; g < 4; ++g) {
      const int row = g * H1 + lane;
      const float* wr = Whh1 + row * H1;
#pragma unroll
      for (int k = 0; k < 18; ++k) wv[g][k] = *(const f32x2*)(wr + 2 * k);
      wB[g] = Wih1[row];
      bias[g] = bih1[row] + bhh1[row];
    }
  } else if (isL2) {
#pragma unroll
    for (int g = 0; g < 4; ++g) {
      const float* wr = Wih2 + g * H1;
#pragma unroll
      for (int k = 0; k < 18; ++k) wv[g][k] = *(const f32x2*)(wr + 2 * k);
      wB[g] = Whh2[g];               // multiplies h2_{t-1}
      bias[g] = bih2[g] + bhh2[g];
    }
  }

  const float* xp = x + (size_t)batch * T_LEN;
  float* outp = out + (size_t)batch * T_LEN;
  const float4* rd4 = (const float4*)(isA ? shh : shr);  // A reads h; L2 reads relu(h)

  // init own region (in-order LDS; only this wave reads it -> no barrier)
  shh[lane] = 0.f;
  shr[lane] = 0.f;
  __builtin_amdgcn_wave_barrier();

  float c = 0.f, hself = 0.f;
  float4 ov = make_float4(0.f, 0.f, 0.f, 0.f);

  auto substep = [&](float xv) {
    const float xin = isL2 ? hself : xv;  // L2's "input" is its own h2_{t-1}
    float4 hq[9];
#pragma unroll
    for (int q = 0; q < 9; ++q) hq[q] = rd4[q];  // broadcast reads (<=2 addrs/wave)
    f32x2 p0 = {hq[0].x, hq[0].y};
    f32x2 a0 = pk_mul(wv[0][0], p0);
    f32x2 a1 = pk_mul(wv[1][0], p0);
    f32x2 a2 = pk_mul(wv[2][0], p0);
    f32x2 a3 = pk_mul(wv[3][0], p0);
    f32x2 p1 = {hq[0].z, hq[0].w};
    a0 = pk_fma(wv[0][1], p1, a0);
    a1 = pk_fma(wv[1][1], p1, a1);
    a2 = pk_fma(wv[2][1], p1, a2);
    a3 = pk_fma(wv[3][1], p1, a3);
#pragma unroll
    for (int q = 1; q < 9; ++q) {
      f32x2 q0 = {hq[q].x, hq[q].y};
      a0 = pk_fma(wv[0][2 * q], q0, a0);
      a1 = pk_fma(wv[1][2 * q], q0, a1);
      a2 = pk_fma(wv[2][2 * q], q0, a2);
      a3 = pk_fma(wv[3][2 * q], q0, a3);
      f32x2 q1 = {hq[q].z, hq[q].w};
      a0 = pk_fma(wv[0][2 * q + 1], q1, a0);
      a1 = pk_fma(wv[1][2 * q + 1], q1, a1);
      a2 = pk_fma(wv[2][2 * q + 1], q1, a2);
      a3 = pk_fma(wv[3][2 * q + 1], q1, a3);
    }
    const float sI = (a0.x + a0.y) + fmaf(xin, wB[0], bias[0]);
    const float sF = (a1.x + a1.y) + fmaf(xin, wB[1], bias[1]);
    const float sG = (a2.x + a2.y) + fmaf(xin, wB[2], bias[2]);
    const float sO = (a3.x + a3.y) + fmaf(xin, wB[3], bias[3]);
    const float I = sigm(sI), F = sigm(sF), G = tanh_fast(sG), O = sigm(sO);
    c = fmaf(F, c, I * G);
    hself = O * tanh_fast(c);
    __builtin_amdgcn_wave_barrier();
    shh[lane] = hself;                 // lanes>=36 write to dump slots (unread)
    shr[lane] = fmaxf(hself, 0.f);
    __builtin_amdgcn_wave_barrier();
  };

  // Peeled iteration 0: computes h1_0 for A-lanes; L2 lane's result is
  // pre-sequence garbage -> reset its state (h2_{-1} = c2_{-1} = 0).
  float4 qc = *(const float4*)xp;  // x[0..3]
  substep(qc.x);
  c = isL2 ? 0.f : c;
  hself = isL2 ? 0.f : hself;
  __builtin_amdgcn_wave_barrier();
  shh[lane] = isA ? hself : 0.f;   // re-zero dump/relu written by garbage step
  shr[lane] = isA ? fmaxf(hself, 0.f) : 0.f;
  __builtin_amdgcn_wave_barrier();

  // Group m: iterations 4m+1 .. 4m+4.
  //   A-lane iteration t computes h1_t (uses x[t]).
  //   L2 lane iteration t computes out[t-1] (uses relu(h1_{t-1}), skewed by 1).
  // -> group m completes out[4m .. 4m+3] exactly.
  for (int t0 = 0; t0 < T_LEN; t0 += 4) {
    const int tn = (t0 + 8 <= T_LEN) ? (t0 + 4) : (T_LEN - 4);
    const float4 qn = *(const float4*)(xp + tn);
    substep(qc.y);
    ov.x = hself;
    substep(qc.z);
    ov.y = hself;
    substep(qc.w);
    ov.z = hself;
    substep(qn.x);  // t=4m+4; at t0=2044 this feeds stale x, result discarded
    ov.w = hself;
    if (isL2) *(float4*)(outp + t0) = ov;
    qc = qn;
  }
}

}  // namespace

extern "C" void kernel_launch(void* const* d_in, const int* in_sizes, int n_in,
                              void* d_out, int out_size, void* d_ws, size_t ws_size,
                              hipStream_t stream) {
  const float* x    = (const float*)d_in[0];
  const float* Wih1 = (const float*)d_in[1];
  const float* Whh1 = (const float*)d_in[2];
  const float* bih1 = (const float*)d_in[3];
  const float* bhh1 = (const float*)d_in[4];
  const float* Wih2 = (const float*)d_in[5];
  const float* Whh2 = (const float*)d_in[6];
  const float* bih2 = (const float*)d_in[7];
  const float* bhh2 = (const float*)d_in[8];
  float* out = (float*)d_out;

  dim3 grid(B_TOT / WPB);  // 512 blocks; 2 blocks/CU -> 8 waves/CU, no barriers
  dim3 block(BLOCK);       // 256 threads = 4 autonomous waves (1 batch each)
  hipLaunchKernelGGL(lstm2_kernel, grid, block, 0, stream,
                     x, Wih1, Whh1, bih1, bhh1, Wih2, Whh2, bih2, bhh2, out);
}

// Round 5
// 986.434 us; speedup vs baseline: 2.5183x; 1.0997x over previous
//
#include <hip/hip_runtime.h>

namespace {

constexpr int T_LEN = 2048;
constexpr int B_TOT = 2048;
constexpr int H1 = 36;      // layer-1 units; lane 36 = layer-2 LSTM
constexpr int WPB = 4;      // waves (=batches) per block
constexpr int BLOCK = 64 * WPB;
constexpr int LDSW = 128;   // _Float16 slots per wave region: h[64] + relu[64]

typedef _Float16 h16x2 __attribute__((ext_vector_type(2)));

__device__ __forceinline__ float fdot2(float wb, float hb, float acc) {
#if __has_builtin(__builtin_amdgcn_fdot2)
  return __builtin_amdgcn_fdot2(__builtin_bit_cast(h16x2, wb),
                                __builtin_bit_cast(h16x2, hb), acc, false);
#else
  float d;
  asm("v_dot2_f32_f16 %0, %1, %2, %3" : "=v"(d) : "v"(wb), "v"(hb), "v"(acc));
  return d;
#endif
}

__device__ __forceinline__ float pack2h(float a, float b) {
  h16x2 t = {(_Float16)a, (_Float16)b};
  return __builtin_bit_cast(float, t);
}

__device__ __forceinline__ float fexp2(float x) { return __builtin_amdgcn_exp2f(x); }
__device__ __forceinline__ float frcp(float x) { return __builtin_amdgcn_rcpf(x); }
__device__ __forceinline__ float sigm(float x) { return frcp(1.f + fexp2(x * -1.44269504f)); }
__device__ __forceinline__ float tanh_fast(float x) {
  return fmaf(2.f, frcp(1.f + fexp2(x * -2.88539008f)), -1.f);  // 2*sigm(2x)-1
}

__global__ __launch_bounds__(BLOCK, 2) void lstm2_kernel(
    const float* __restrict__ x, const float* __restrict__ Wih1,
    const float* __restrict__ Whh1, const float* __restrict__ bih1,
    const float* __restrict__ bhh1, const float* __restrict__ Wih2,
    const float* __restrict__ Whh2, const float* __restrict__ bih2,
    const float* __restrict__ bhh2, float* __restrict__ out)
{
  __shared__ __align__(16) _Float16 sh[WPB * LDSW];

  const int tid = threadIdx.x;
  const int w = tid >> 6;
  const int lane = tid & 63;
  const int batch = blockIdx.x * WPB + w;

  _Float16* hh = sh + w * LDSW;  // h1 (fp16), slots 0..35 live, 36..63 dump
  _Float16* hr = hh + 64;        // relu(h1) (fp16) for the L2 lane

  const bool isA = lane < H1;
  const bool isL2 = lane == H1;

  // Per-lane weights as packed-fp16 pairs (1 VGPR each):
  // lane u<36 -> 4 rows of W_hh1; lane 36 -> 4 rows of W_ih2.
  float w2[4][18];
  float wB[4] = {0, 0, 0, 0}, bias[4] = {0, 0, 0, 0};
#pragma unroll
  for (int g = 0; g < 4; ++g)
#pragma unroll
    for (int k = 0; k < 18; ++k) w2[g][k] = 0.f;

  if (isA) {
#pragma unroll
    for (int g = 0; g < 4; ++g) {
      const int row = g * H1 + lane;
      const float* wr = Whh1 + row * H1;
#pragma unroll
      for (int k = 0; k < 18; ++k) w2[g][k] = pack2h(wr[2 * k], wr[2 * k + 1]);
      wB[g] = Wih1[row];
      bias[g] = bih1[row] + bhh1[row];
    }
  } else if (isL2) {
#pragma unroll
    for (int g = 0; g < 4; ++g) {
      const float* wr = Wih2 + g * H1;
#pragma unroll
      for (int k = 0; k < 18; ++k) w2[g][k] = pack2h(wr[2 * k], wr[2 * k + 1]);
      wB[g] = Whh2[g];  // multiplies h2_{t-1} (fp32)
      bias[g] = bih2[g] + bhh2[g];
    }
  }

  const float* xp = x + (size_t)batch * T_LEN;
  float* outp = out + (size_t)batch * T_LEN;
  const char* rd = (const char*)(isA ? hh : hr);  // A reads h; L2 reads relu(h)

  hh[lane] = (_Float16)0.f;  // h0 = 0 (own region; in-order LDS, no barrier)
  hr[lane] = (_Float16)0.f;
  __builtin_amdgcn_wave_barrier();

  float c = 0.f, hself = 0.f;
  float4 ov = make_float4(0.f, 0.f, 0.f, 0.f);

  auto substep = [&](float xv) {
    const float xin = isL2 ? hself : xv;  // L2's "input" is its own h2_{t-1}
    // 36 fp16 h values = 72 B: 4x b128 + 1x b64 (broadcast; <=2 addrs/wave).
    float f[18];
    const float4 q0 = *(const float4*)(rd);
    const float4 q1 = *(const float4*)(rd + 16);
    const float4 q2 = *(const float4*)(rd + 32);
    const float4 q3 = *(const float4*)(rd + 48);
    const float2 q4 = *(const float2*)(rd + 64);
    f[0] = q0.x;  f[1] = q0.y;  f[2] = q0.z;  f[3] = q0.w;
    f[4] = q1.x;  f[5] = q1.y;  f[6] = q1.z;  f[7] = q1.w;
    f[8] = q2.x;  f[9] = q2.y;  f[10] = q2.z; f[11] = q2.w;
    f[12] = q3.x; f[13] = q3.y; f[14] = q3.z; f[15] = q3.w;
    f[16] = q4.x; f[17] = q4.y;
    float a0 = fmaf(xin, wB[0], bias[0]);
    float a1 = fmaf(xin, wB[1], bias[1]);
    float a2 = fmaf(xin, wB[2], bias[2]);
    float a3 = fmaf(xin, wB[3], bias[3]);
#pragma unroll
    for (int k = 0; k < 18; ++k) {
      a0 = fdot2(w2[0][k], f[k], a0);
      a1 = fdot2(w2[1][k], f[k], a1);
      a2 = fdot2(w2[2][k], f[k], a2);
      a3 = fdot2(w2[3][k], f[k], a3);
    }
    const float I = sigm(a0), F = sigm(a1), G = tanh_fast(a2), O = sigm(a3);
    c = fmaf(F, c, I * G);
    hself = O * tanh_fast(c);
    __builtin_amdgcn_wave_barrier();
    hh[lane] = (_Float16)hself;            // lanes>=36 hit dump slots
    hr[lane] = (_Float16)fmaxf(hself, 0.f);
    __builtin_amdgcn_wave_barrier();
  };

  // Peeled iteration 0: A-lanes compute h1_0; L2 lane's result is pre-sequence
  // garbage -> reset its state and re-zero what the garbage step wrote.
  float4 qc = *(const float4*)xp;  // x[0..3]
  substep(qc.x);
  c = isL2 ? 0.f : c;
  hself = isL2 ? 0.f : hself;
  __builtin_amdgcn_wave_barrier();
  hh[lane] = isA ? (_Float16)hself : (_Float16)0.f;
  hr[lane] = isA ? (_Float16)fmaxf(hself, 0.f) : (_Float16)0.f;
  __builtin_amdgcn_wave_barrier();

  // Group m: iterations 4m+1 .. 4m+4.
  //   A-lane iteration t computes h1_t (uses x[t]).
  //   L2 lane iteration t computes out[t-1] (reads relu(h1_{t-1}), skew 1).
  // -> group m completes out[4m .. 4m+3].
  for (int t0 = 0; t0 < T_LEN; t0 += 4) {
    const int tn = (t0 + 8 <= T_LEN) ? (t0 + 4) : (T_LEN - 4);
    const float4 qn = *(const float4*)(xp + tn);
    substep(qc.y);
    ov.x = hself;
    substep(qc.z);
    ov.y = hself;
    substep(qc.w);
    ov.z = hself;
    substep(qn.x);  // t=4m+4; at t0=2044 feeds stale x, result discarded
    ov.w = hself;
    if (isL2) *(float4*)(outp + t0) = ov;
    qc = qn;
  }
}

}  // namespace

extern "C" void kernel_launch(void* const* d_in, const int* in_sizes, int n_in,
                              void* d_out, int out_size, void* d_ws, size_t ws_size,
                              hipStream_t stream) {
  const float* x    = (const float*)d_in[0];
  const float* Wih1 = (const float*)d_in[1];
  const float* Whh1 = (const float*)d_in[2];
  const float* bih1 = (const float*)d_in[3];
  const float* bhh1 = (const float*)d_in[4];
  const float* Wih2 = (const float*)d_in[5];
  const float* Whh2 = (const float*)d_in[6];
  const float* bih2 = (const float*)d_in[7];
  const float* bhh2 = (const float*)d_in[8];
  float* out = (float*)d_out;

  dim3 grid(B_TOT / WPB);  // 512 blocks; 2 blocks/CU -> 8 waves/CU, no barriers
  dim3 block(BLOCK);       // 256 threads = 4 autonomous waves (1 batch each)
  hipLaunchKernelGGL(lstm2_kernel, grid, block, 0, stream,
                     x, Wih1, Whh1, bih1, bhh1, Wih2, Whh2, bih2, bhh2, out);
}